// Round 1
// baseline (332.656 us; speedup 1.0000x reference)
//
#include <hip/hip_runtime.h>

// PointPillarScatter: scatter V=40000 pillars (64ch fp32) to 512x512 canvas,
// 1x1 conv (64x64) + bias, broadcast to B=4.  Output (4,64,512,512) fp32.
//
// v2: fully fused. Tiny scatter kernel builds a u16 inverse map; one writer
// kernel computes the conv per position on the fly (no res intermediate,
// -20.8 MB HBM) and writes the output with float4 nontemporal stores.

#define V_PILLARS 40000
#define XDIM 512
#define YDIM 512
#define C 64          // IN_C == OUT_C == 64
#define BATCH 4
#define PLANE (XDIM * YDIM)   // 262144 floats per (b,o) plane

typedef float f32x4 __attribute__((ext_vector_type(4)));

// ---------------- K1: build u16 inverse map ---------------------------------
// map pre-filled with 0xFF (sentinel 0xFFFF). p fits in u16 (40000 < 65535).
__global__ __launch_bounds__(256) void k_scatter(
    const int* __restrict__ vidx,            // (V,2)
    unsigned short* __restrict__ map)        // (512*512)
{
    const int p = blockIdx.x * 256 + threadIdx.x;
    if (p < V_PILLARS) {
        const int2 xy = ((const int2*)vidx)[p];   // coalesced 8 B
        if (xy.x >= 0 && xy.x < XDIM && xy.y >= 0 && xy.y < YDIM)
            map[xy.x * YDIM + xy.y] = (unsigned short)p;
    }
}

// ---------------- K2: fused conv + single-pass output writer ----------------
// grid: 4096 blocks (x in 0..511, y-chunk in 0..7) x 256 threads.
// Phase A (conv): wave w handles positions y = w*16..w*16+15, lane == o.
//   Valid position: broadcast-load the pillar's 64 features (16x float4,
//   same addr across lanes) and dot with this lane's weight row (held in
//   16 float4 regs, staged once through LDS). Empty position: bias.
//   Results land in sres[y][o] (pad 65 -> 2-way bank alias, free).
// Phase B (write): wave w handles o = w*16..w*16+15. lane = o_sub*16 + yq;
//   each thread assembles float4 along y (4 LDS dwords, 2-way alias, free)
//   and issues 16 nontemporal float4 stores (4 o-iters x 4 batches) —
//   1 KB per wave-store, 4x fewer VMEM instrs than dword stores.
__global__ __launch_bounds__(256) void k_conv_write(
    const float* __restrict__ pf,            // (V,64)
    const float* __restrict__ cw,            // (64,64) row-major [o][c]
    const float* __restrict__ cb,            // (64,)
    const unsigned short* __restrict__ map,  // (512*512)
    float* __restrict__ out)                 // (4,64,512,512)
{
    __shared__ float swt[64 * 68];           // conv_w, rows padded to 68
    __shared__ float sres[64][65];           // [y][o], pad 65
    __shared__ unsigned short smap[64];

    const int t    = threadIdx.x;
    const int lane = t & 63;
    const int w    = t >> 6;
    const int x  = (int)blockIdx.x >> 3;
    const int y0 = ((int)blockIdx.x & 7) << 6;

    if (t < 64) smap[t] = map[x * YDIM + y0 + t];

    // cooperative coalesced load of conv_w (16 KB) into LDS, padded rows
    for (int i = t; i < 64 * 16; i += 256) {
        const int o = i >> 4, j = i & 15;
        float4 v = ((const float4*)cw)[i];          // i == o*16 + j
        *((float4*)&swt[o * 68 + 4 * j]) = v;
    }
    __syncthreads();

    // each lane pulls its weight row (one-time LDS reads, amortized)
    float4 wr[16];
#pragma unroll
    for (int j = 0; j < 16; j++)
        wr[j] = *((const float4*)&swt[lane * 68 + 4 * j]);
    const float bias = cb[lane];

    // ---- Phase A: per-position conv (v is wave-uniform -> uniform branch)
#pragma unroll
    for (int i = 0; i < 16; i++) {
        const int y = w * 16 + i;
        const int v = smap[y];
        float acc = bias;
        if (v != 0xFFFF) {
            const float4* a4 = (const float4*)(pf + (size_t)v * C);
#pragma unroll
            for (int j = 0; j < 16; j++) {
                const float4 a = a4[j];
                acc += a.x * wr[j].x + a.y * wr[j].y + a.z * wr[j].z + a.w * wr[j].w;
            }
        }
        sres[y][lane] = acc;
    }
    __syncthreads();

    // ---- Phase B: coalesced float4 output stores
    const int o_sub = lane >> 4;             // 0..3
    const int yq    = lane & 15;             // 0..15
    const size_t ybase = (size_t)x * YDIM + y0 + 4 * yq;
#pragma unroll
    for (int it = 0; it < 4; it++) {
        const int o = w * 16 + it * 4 + o_sub;
        f32x4 val;
        val.x = sres[4 * yq + 0][o];
        val.y = sres[4 * yq + 1][o];
        val.z = sres[4 * yq + 2][o];
        val.w = sres[4 * yq + 3][o];
        const size_t idx = (size_t)o * PLANE + ybase;     // float index
#pragma unroll
        for (int b = 0; b < BATCH; b++) {
            __builtin_nontemporal_store(
                val, (f32x4*)(out + idx + (size_t)b * C * PLANE));
        }
    }
}

extern "C" void kernel_launch(void* const* d_in, const int* in_sizes, int n_in,
                              void* d_out, int out_size, void* d_ws, size_t ws_size,
                              hipStream_t stream) {
    const float* pf   = (const float*)d_in[0];  // (40000,64)
    const float* cw   = (const float*)d_in[1];  // (64,64)
    const float* cb   = (const float*)d_in[2];  // (64,)
    const int*   vidx = (const int*)d_in[3];    // (40000,2)
    float* out = (float*)d_out;

    // workspace: u16 inverse map, 512 KB
    unsigned short* map = (unsigned short*)d_ws;

    hipMemsetAsync(map, 0xFF, PLANE * sizeof(unsigned short), stream);  // = 0xFFFF

    k_scatter<<<(V_PILLARS + 255) / 256, 256, 0, stream>>>(vidx, map);
    k_conv_write<<<XDIM * (YDIM / 64), 256, 0, stream>>>(pf, cw, cb, map, out);
}